// Round 5
// baseline (156.016 us; speedup 1.0000x reference)
//
#include <hip/hip_runtime.h>
#include <cstdint>
#include <cstddef>

typedef __bf16 bf16_t;
typedef __bf16 bf16x4 __attribute__((ext_vector_type(4)));
typedef __bf16 bf16x8 __attribute__((ext_vector_type(8)));
typedef float f32x4 __attribute__((ext_vector_type(4)));

#define M_DIM 4096
#define K_DIM 2048
#define N_DIM 2048
#define KCAT 4096  // fused K: [inputs | Z] and [fwd_w ; rec_w]

// ---- GEMM geometry: 4 waves, per-wave 128x64 output ----
#define BM 256
#define BN 128
#define BK 64
#define NT (KCAT / BK)                 // 64 K-tiles
#define A_ELEMS (BM * BK)              // 16384 bf16 (32768 B)
#define B_ELEMS (BN * BK)              // 8192 bf16 (16384 B)
#define PER_BUF (A_ELEMS + B_ELEMS)    // 24576 bf16 = 49152 B
#define B_OFF A_ELEMS
#define LDS_BYTES (3 * PER_BUF * 2)    // 147456 B (3 buffers)

#define MFMA16(a, b, c) \
  __builtin_amdgcn_mfma_f32_16x16x32_bf16((a), (b), (c), 0, 0, 0)

// async global->LDS, 16B/lane (HW: LDS dest = wave-uniform base + lane*16)
__device__ __forceinline__ void gload_lds16(const bf16_t* g, bf16_t* l) {
  __builtin_amdgcn_global_load_lds(
      (const __attribute__((address_space(1))) void*)g,
      (__attribute__((address_space(3))) void*)l, 16, 0, 0);
}

// ---------------------------------------------------------------------------
// Prepass 1: f32 -> bf16, A_cat [M][KCAT] = [inputs | Z], k-contiguous.
// ---------------------------------------------------------------------------
__global__ __launch_bounds__(256) void convert_acat(
    const float* __restrict__ inputs, const float* __restrict__ Z,
    bf16_t* __restrict__ acat) {
  const int g = blockIdx.x * 256 + threadIdx.x;
  const int half = g >> 20;
  const int i = g & 1048575;
  const int m = i >> 8;
  const int kc = (i & 255) * 8;
  const float* src = (half ? Z : inputs) + (size_t)m * K_DIM + kc;
  const float4 v0 = *reinterpret_cast<const float4*>(src);
  const float4 v1 = *reinterpret_cast<const float4*>(src + 4);
  bf16x8 o;
  o[0] = (bf16_t)v0.x; o[1] = (bf16_t)v0.y;
  o[2] = (bf16_t)v0.z; o[3] = (bf16_t)v0.w;
  o[4] = (bf16_t)v1.x; o[5] = (bf16_t)v1.y;
  o[6] = (bf16_t)v1.z; o[7] = (bf16_t)v1.w;
  *reinterpret_cast<bf16x8*>(
      &acat[(size_t)m * KCAT + (size_t)half * K_DIM + kc]) = o;
}

// ---------------------------------------------------------------------------
// Prepass 2: transpose+convert [K][N] f32 weights -> W_cat^T [N][KCAT] bf16.
// ---------------------------------------------------------------------------
__global__ __launch_bounds__(256) void transpose_wcat(
    const float* __restrict__ w1, const float* __restrict__ w2,
    bf16_t* __restrict__ wcat) {
  __shared__ float tile[64][65];
  const int t = threadIdx.x;
  const int half = blockIdx.z;
  const float* __restrict__ src = half ? w2 : w1;
  const int k0 = blockIdx.y * 64;
  const int n0 = blockIdx.x * 64;
#pragma unroll
  for (int p = 0; p < 4; ++p) {
    const int r = p * 16 + (t >> 4);
    const int c = (t & 15) * 4;
    const float4 v = *reinterpret_cast<const float4*>(
        &src[(size_t)(k0 + r) * N_DIM + n0 + c]);
    tile[r][c + 0] = v.x;
    tile[r][c + 1] = v.y;
    tile[r][c + 2] = v.z;
    tile[r][c + 3] = v.w;
  }
  __syncthreads();
#pragma unroll
  for (int p = 0; p < 4; ++p) {
    const int n = p * 16 + (t >> 4);
    const int c = (t & 15) * 4;
    bf16x4 o;
    o[0] = (bf16_t)tile[c + 0][n];
    o[1] = (bf16_t)tile[c + 1][n];
    o[2] = (bf16_t)tile[c + 2][n];
    o[3] = (bf16_t)tile[c + 3][n];
    *reinterpret_cast<bf16x4*>(
        &wcat[(size_t)(n0 + n) * KCAT + (size_t)half * K_DIM + k0 + c]) = o;
  }
}

// ---------------------------------------------------------------------------
// Main GEMM: 4 waves (1/SIMD), per-wave 128x64, BK=64, 3 LDS buffers.
// Half-K-tile software pipeline (fits registers):
//   phase A: MFMA(ks0,F0) || ds_read(t,ks1)->F1
//   boundary: s_waitcnt vmcnt(12) lgkmcnt(0); s_barrier  (ordering proven)
//   phase B: stage t+3 -> buf[t%3]; MFMA(ks1,F1) || ds_read(t+1,ks0)->F0
// T2 LDS XOR-swizzle (verified 0 conflicts), T1 XCD swizzle.
// Epilogue: acc -> wave-private LDS (stride 68) -> f32x4 vectorized LIF.
// ---------------------------------------------------------------------------
__global__ __launch_bounds__(256, 1) void lif_gemm_hs(
    const bf16_t* __restrict__ A, const bf16_t* __restrict__ W,
    const float* __restrict__ Iin, const float* __restrict__ Vin,
    const float* __restrict__ Zin,
    float* __restrict__ outZ, float* __restrict__ outI,
    float* __restrict__ outV) {
  extern __shared__ __align__(16) bf16_t lds[];

  const int tid = threadIdx.x;
  const int lane = tid & 63;
  const int wave = tid >> 6;   // 0..3
  const int wm = wave >> 1;    // 0..1 (M half: 128 rows)
  const int wn = wave & 1;     // 0..1 (N half: 64 cols)
  const int l15 = lane & 15;
  const int l4 = lane >> 4;

  // T1: XCD-aware block swizzle (256 blocks, bijective)
  const int bid = blockIdx.x;
  const int swz = (bid & 7) * 32 + (bid >> 3);
  const int m0 = (swz >> 4) * BM;  // 16 m-tiles
  const int n0 = (swz & 15) * BN;  // 16 n-tiles

  // ---- staging addresses (pre-swizzled global source, linear LDS dest) ----
  const int lr = lane >> 3;        // row-in-group 0..7
  const int sg = (lane & 7) ^ lr;  // swizzled logical 16B-slot
  const bf16_t* aSrc[8];
  const bf16_t* bSrc[4];
  int aDst[8], bDst[4];
#pragma unroll
  for (int i = 0; i < 8; ++i) {
    const int r = wave * 64 + i * 8 + lr;  // A rows 0..255
    aSrc[i] = A + (size_t)(m0 + r) * KCAT + sg * 8;
    aDst[i] = r * BK + (lane & 7) * 8;     // = uniform + lane*16B
  }
#pragma unroll
  for (int i = 0; i < 4; ++i) {
    const int r = wave * 32 + i * 8 + lr;  // B rows 0..127
    bSrc[i] = W + (size_t)(n0 + r) * KCAT + sg * 8;
    bDst[i] = B_OFF + r * BK + (lane & 7) * 8;
  }

  // ---- fragment lane-bases (swizzled read), elements within buffer ----
  int aBase[2], bBase[2];
#pragma unroll
  for (int ks = 0; ks < 2; ++ks) {
    const int phys = (l4 + ks * 4) ^ (l15 & 7);
    aBase[ks] = (wm * 128 + l15) * BK + phys * 8;
    bBase[ks] = B_OFF + (wn * 64 + l15) * BK + phys * 8;
  }

  f32x4 acc[8][4];
#pragma unroll
  for (int i = 0; i < 8; ++i)
#pragma unroll
    for (int j = 0; j < 4; ++j)
#pragma unroll
      for (int e = 0; e < 4; ++e) acc[i][j][e] = 0.0f;

  bf16x8 fA0[8], fB0[4], fA1[8], fB1[4];

  // ---- prologue: stage tiles 0,1,2 into bufs 0,1,2 ----
#pragma unroll
  for (int tt = 0; tt < 3; ++tt) {
    bf16_t* sp = lds + tt * PER_BUF;
#pragma unroll
    for (int i = 0; i < 8; ++i) gload_lds16(aSrc[i] + tt * BK, sp + aDst[i]);
#pragma unroll
    for (int i = 0; i < 4; ++i) gload_lds16(bSrc[i] + tt * BK, sp + bDst[i]);
  }
  asm volatile("s_waitcnt vmcnt(24)" ::: "memory");  // my tile-0 landed
  __builtin_amdgcn_sched_barrier(0);
  __builtin_amdgcn_s_barrier();                      // => everyone's tile 0
  __builtin_amdgcn_sched_barrier(0);

  // read (0, ks0) -> F0
#pragma unroll
  for (int i = 0; i < 8; ++i)
    fA0[i] = *reinterpret_cast<const bf16x8*>(lds + aBase[0] + i * 1024);
#pragma unroll
  for (int i = 0; i < 4; ++i)
    fB0[i] = *reinterpret_cast<const bf16x8*>(lds + bBase[0] + i * 1024);

  int bufR = 0;  // buffer holding tile t
  for (int t = 0; t < NT; ++t) {
    bf16_t* bufC = lds + bufR * PER_BUF;
    const int bufNi = (bufR == 2) ? 0 : bufR + 1;
    const bf16_t* bufN = lds + bufNi * PER_BUF;

    // ---------- phase A: ds_read (t,ks1)->F1 ; MFMA ks0 (F0) ----------
#pragma unroll
    for (int i = 0; i < 8; ++i)
      fA1[i] = *reinterpret_cast<const bf16x8*>(bufC + aBase[1] + i * 1024);
#pragma unroll
    for (int i = 0; i < 4; ++i)
      fB1[i] = *reinterpret_cast<const bf16x8*>(bufC + bBase[1] + i * 1024);
#pragma unroll
    for (int mi = 0; mi < 8; ++mi)
#pragma unroll
      for (int ni = 0; ni < 4; ++ni)
        acc[mi][ni] = MFMA16(fA0[mi], fB0[ni], acc[mi][ni]);

    // ---------- boundary: prove (t+1) landed for ALL waves; all reads of
    // buf[t%3] drained by every wave before anyone stages into it ----------
    __builtin_amdgcn_sched_barrier(0);
    if (t < NT - 2) {
      asm volatile("s_waitcnt vmcnt(12) lgkmcnt(0)" ::: "memory");
    } else {
      asm volatile("s_waitcnt vmcnt(0) lgkmcnt(0)" ::: "memory");
    }
    __builtin_amdgcn_sched_barrier(0);
    __builtin_amdgcn_s_barrier();
    __builtin_amdgcn_sched_barrier(0);

    // ---------- phase B: stage t+3 -> buf[t%3]; ds_read (t+1,ks0)->F0;
    //            MFMA ks1 (F1) ----------
    if (t + 3 < NT) {
      const int ktN = (t + 3) * BK;
      bf16_t* sp = bufC;  // buf[(t+3)%3] == buf[t%3]
#pragma unroll
      for (int i = 0; i < 8; ++i) gload_lds16(aSrc[i] + ktN, sp + aDst[i]);
#pragma unroll
      for (int i = 0; i < 4; ++i) gload_lds16(bSrc[i] + ktN, sp + bDst[i]);
    }
    if (t + 1 < NT) {
#pragma unroll
      for (int i = 0; i < 8; ++i)
        fA0[i] = *reinterpret_cast<const bf16x8*>(bufN + aBase[0] + i * 1024);
#pragma unroll
      for (int i = 0; i < 4; ++i)
        fB0[i] = *reinterpret_cast<const bf16x8*>(bufN + bBase[0] + i * 1024);
    }
#pragma unroll
    for (int mi = 0; mi < 8; ++mi)
#pragma unroll
      for (int ni = 0; ni < 4; ++ni)
        acc[mi][ni] = MFMA16(fA1[mi], fB1[ni], acc[mi][ni]);
    __builtin_amdgcn_sched_barrier(0);

    bufR = bufNi;
  }

  // ---- vectorized LIF epilogue: acc -> wave-private LDS -> f32x4 I/O ----
  // After the final barrier (inside t=NT-1), no wave reads K-buffers again.
  float* sw = reinterpret_cast<float*>(lds) + (size_t)wave * (128 * 68);
#pragma unroll
  for (int mi = 0; mi < 8; ++mi)
#pragma unroll
    for (int j = 0; j < 4; ++j)
#pragma unroll
      for (int ni = 0; ni < 4; ++ni)
        sw[(mi * 16 + l4 * 4 + j) * 68 + ni * 16 + l15] = acc[mi][ni][j];
  // wave-private region: no barrier needed (compiler waits lgkm on dep)

  const float alpha = 0.90483741803595957f;  // exp(-0.1)
  const float beta = 0.81873075307798182f;   // exp(-0.2)
  const int erow = lane >> 2;       // 0..15
  const int ecol = (lane & 3) * 16; // 0,16,32,48
#pragma unroll
  for (int rr = 0; rr < 8; ++rr) {
    const int row = rr * 16 + erow;
    const float* srow = sw + row * 68 + ecol;
    const size_t gb =
        (size_t)(m0 + wm * 128 + row) * N_DIM + n0 + wn * 64 + ecol;
#pragma unroll
    for (int cc = 0; cc < 4; ++cc) {
      const f32x4 av = *reinterpret_cast<const f32x4*>(srow + cc * 4);
      const f32x4 iv = *reinterpret_cast<const f32x4*>(Iin + gb + cc * 4);
      const f32x4 vv = *reinterpret_cast<const f32x4*>(Vin + gb + cc * 4);
      const f32x4 zv = *reinterpret_cast<const f32x4*>(Zin + gb + cc * 4);
      f32x4 nI, nV, nZ;
#pragma unroll
      for (int e = 0; e < 4; ++e) {
        nI[e] = alpha * iv[e] + av[e];
        nV[e] = (beta * vv[e] + nI[e]) * (1.0f - zv[e]);
        nZ[e] = (nV[e] > 1.0f) ? 1.0f : 0.0f;
      }
      *reinterpret_cast<f32x4*>(outI + gb + cc * 4) = nI;
      *reinterpret_cast<f32x4*>(outV + gb + cc * 4) = nV;
      *reinterpret_cast<f32x4*>(outZ + gb + cc * 4) = nZ;
    }
  }
}

extern "C" void kernel_launch(void* const* d_in, const int* in_sizes, int n_in,
                              void* d_out, int out_size, void* d_ws,
                              size_t ws_size, hipStream_t stream) {
  const float* inputs = (const float*)d_in[0];
  const float* I = (const float*)d_in[1];
  const float* V = (const float*)d_in[2];
  const float* Z = (const float*)d_in[3];
  const float* fwd_w = (const float*)d_in[4];
  const float* rec_w = (const float*)d_in[5];

  float* outZ = (float*)d_out;
  float* outI = outZ + (size_t)M_DIM * N_DIM;
  float* outV = outI + (size_t)M_DIM * N_DIM;

  const size_t ACAT_BYTES = (size_t)M_DIM * KCAT * sizeof(bf16_t);  // 32 MiB
  bf16_t* acat = (bf16_t*)d_ws;
  bf16_t* wcat = (bf16_t*)((char*)d_ws + ACAT_BYTES);

  hipLaunchKernelGGL(convert_acat, dim3(8192), dim3(256), 0, stream, inputs, Z,
                     acat);
  hipLaunchKernelGGL(transpose_wcat, dim3(N_DIM / 64, K_DIM / 64, 2), dim3(256),
                     0, stream, fwd_w, rec_w, wcat);

  (void)hipFuncSetAttribute(reinterpret_cast<const void*>(lif_gemm_hs),
                            hipFuncAttributeMaxDynamicSharedMemorySize,
                            LDS_BYTES);
  hipLaunchKernelGGL(lif_gemm_hs, dim3((M_DIM / BM) * (N_DIM / BN)), dim3(256),
                     LDS_BYTES, stream, acat, wcat, I, V, Z, outZ, outI, outV);
}

// Round 6
// 106.183 us; speedup vs baseline: 1.4693x; 1.4693x over previous
//
#include <hip/hip_runtime.h>
#include <cstdint>
#include <cstddef>

typedef __bf16 bf16_t;
typedef __bf16 bf16x4 __attribute__((ext_vector_type(4)));
typedef __bf16 bf16x8 __attribute__((ext_vector_type(8)));
typedef float f32x4 __attribute__((ext_vector_type(4)));

#define M_DIM 4096
#define K_DIM 2048
#define N_DIM 2048

// ---- fwd GEMM geometry: TLP regime (1024 blocks, 3-4/CU) ----
#define BM 128
#define BN 64
#define BK 64
#define KT (K_DIM / BK)        // 32 K-tiles
#define A_EL (BM * BK)         // 8192 bf16 (16 KiB)
#define B_EL (BN * BK)         // 4096 bf16 (8 KiB)
#define B_OFF A_EL

#define ZCAP 64                // spike indices kept per row; overflow -> dense

#define MFMA16(a, b, c) \
  __builtin_amdgcn_mfma_f32_16x16x32_bf16((a), (b), (c), 0, 0, 0)

__device__ __forceinline__ void gload_lds16(const bf16_t* g, bf16_t* l) {
  __builtin_amdgcn_global_load_lds(
      (const __attribute__((address_space(1))) void*)g,
      (__attribute__((address_space(3))) void*)l, 16, 0, 0);
}

// ---------------------------------------------------------------------------
// Prepass 1: inputs f32 [M][K] -> bf16 (k-contiguous), vectorized.
// ---------------------------------------------------------------------------
__global__ __launch_bounds__(256) void convert_a(
    const float* __restrict__ inputs, bf16_t* __restrict__ abf) {
  const int g = blockIdx.x * 256 + threadIdx.x;  // 1M threads
  const size_t base = (size_t)g * 8;
  const float4 v0 = *reinterpret_cast<const float4*>(inputs + base);
  const float4 v1 = *reinterpret_cast<const float4*>(inputs + base + 4);
  bf16x8 o;
  o[0] = (bf16_t)v0.x; o[1] = (bf16_t)v0.y;
  o[2] = (bf16_t)v0.z; o[3] = (bf16_t)v0.w;
  o[4] = (bf16_t)v1.x; o[5] = (bf16_t)v1.y;
  o[6] = (bf16_t)v1.z; o[7] = (bf16_t)v1.w;
  *reinterpret_cast<bf16x8*>(abf + base) = o;
}

// ---------------------------------------------------------------------------
// Prepass 2: transpose+convert fwd_w [K][N] f32 -> [N][K] bf16.
// ---------------------------------------------------------------------------
__global__ __launch_bounds__(256) void transpose_w(
    const float* __restrict__ src, bf16_t* __restrict__ dst) {
  __shared__ float tile[64][65];
  const int t = threadIdx.x;
  const int k0 = blockIdx.y * 64;
  const int n0 = blockIdx.x * 64;
#pragma unroll
  for (int p = 0; p < 4; ++p) {
    const int r = p * 16 + (t >> 4);
    const int c = (t & 15) * 4;
    const float4 v = *reinterpret_cast<const float4*>(
        &src[(size_t)(k0 + r) * N_DIM + n0 + c]);
    tile[r][c + 0] = v.x;
    tile[r][c + 1] = v.y;
    tile[r][c + 2] = v.z;
    tile[r][c + 3] = v.w;
  }
  __syncthreads();
#pragma unroll
  for (int p = 0; p < 4; ++p) {
    const int n = p * 16 + (t >> 4);
    const int c = (t & 15) * 4;
    bf16x4 o;
    o[0] = (bf16_t)tile[c + 0][n];
    o[1] = (bf16_t)tile[c + 1][n];
    o[2] = (bf16_t)tile[c + 2][n];
    o[3] = (bf16_t)tile[c + 3][n];
    *reinterpret_cast<bf16x4*>(&dst[(size_t)(n0 + n) * K_DIM + k0 + c]) = o;
  }
}

// ---------------------------------------------------------------------------
// Prepass 3: event-driven compaction of Z. One wave per batch row: counts
// nonzeros, stores up to ZCAP (index,value) pairs. Overflow rows (cnt>ZCAP)
// are handled by a dense fallback in the GEMM epilogue (general correctness).
// ---------------------------------------------------------------------------
__global__ __launch_bounds__(256) void scan_z(
    const float* __restrict__ Z, int* __restrict__ zcnt,
    int* __restrict__ zidx, float* __restrict__ zval) {
  const int row = blockIdx.x * 4 + (threadIdx.x >> 6);
  const int lane = threadIdx.x & 63;
  const float* zr = Z + (size_t)row * N_DIM;
  int local = 0;
#pragma unroll
  for (int c = 0; c < 32; c += 4) {
    const f32x4 v = *reinterpret_cast<const f32x4*>(zr + lane * 32 + c);
#pragma unroll
    for (int e = 0; e < 4; ++e) local += (v[e] != 0.0f) ? 1 : 0;
  }
  // inclusive prefix over 64 lanes
  int pre = local;
#pragma unroll
  for (int d = 1; d < 64; d <<= 1) {
    const int up = __shfl_up(pre, d, 64);
    if (lane >= d) pre += up;
  }
  const int total = __shfl(pre, 63, 64);
  if (lane == 0) zcnt[row] = total;
  if (total > 0 && total <= ZCAP) {
    int wpos = pre - local;  // exclusive prefix
    int* zi = zidx + (size_t)row * ZCAP;
    float* zv = zval + (size_t)row * ZCAP;
    for (int c = lane * 32; c < lane * 32 + 32; ++c) {
      const float v = zr[c];
      if (v != 0.0f) {
        zi[wpos] = c;
        zv[wpos] = v;
        ++wpos;
      }
    }
  }
}

// ---------------------------------------------------------------------------
// Fwd GEMM + sparse recurrent + LIF epilogue.
// BM=128 x BN=64, BK=64, 4 waves (2x2, per-wave 64x32), m97 2-barrier loop,
// global_load_lds w=16, XOR-swizzled LDS (verified 0 conflicts), 24 KiB LDS.
// ---------------------------------------------------------------------------
__global__ __launch_bounds__(256, 2) void lif_gemm_tlp(
    const bf16_t* __restrict__ A, const bf16_t* __restrict__ W,
    const float* __restrict__ recw,
    const int* __restrict__ zcnt, const int* __restrict__ zidx,
    const float* __restrict__ zval,
    const float* __restrict__ Iin, const float* __restrict__ Vin,
    const float* __restrict__ Zin,
    float* __restrict__ outZ, float* __restrict__ outI,
    float* __restrict__ outV) {
  __shared__ __align__(16) bf16_t lds[A_EL + B_EL];

  const int tid = threadIdx.x;
  const int lane = tid & 63;
  const int wave = tid >> 6;   // 0..3
  const int wm = wave >> 1;    // 0..1 (64-row half)
  const int wn = wave & 1;     // 0..1 (32-col half)
  const int l15 = lane & 15;
  const int l4 = lane >> 4;

  // T1: XCD-aware swizzle (1024 blocks, 1024%8==0 -> bijective)
  const int bid = blockIdx.x;
  const int swz = (bid & 7) * 128 + (bid >> 3);
  const int m0 = (swz >> 5) * BM;  // 32 m-tiles
  const int n0 = (swz & 31) * BN;  // 32 n-tiles

  // ---- staging (pre-swizzled global source, linear LDS dest; rule 21) ----
  const int lr = lane >> 3;        // 0..7
  const int sg = (lane & 7) ^ lr;  // swizzled 16B-slot in global k
  const bf16_t* aSrc[4];
  const bf16_t* bSrc[2];
  int aDst[4], bDst[2];
#pragma unroll
  for (int i = 0; i < 4; ++i) {
    const int r = wave * 32 + i * 8 + lr;  // A rows 0..127
    aSrc[i] = A + (size_t)(m0 + r) * K_DIM + sg * 8;
    aDst[i] = r * BK + (lane & 7) * 8;
  }
#pragma unroll
  for (int i = 0; i < 2; ++i) {
    const int r = wave * 16 + i * 8 + lr;  // B rows 0..63
    bSrc[i] = W + (size_t)(n0 + r) * K_DIM + sg * 8;
    bDst[i] = B_OFF + r * BK + (lane & 7) * 8;
  }

  // ---- swizzled fragment read bases ----
  int aBase[2], bBase[2];
#pragma unroll
  for (int ks = 0; ks < 2; ++ks) {
    const int phys = (l4 + ks * 4) ^ (l15 & 7);
    aBase[ks] = (wm * 64 + l15) * BK + phys * 8;
    bBase[ks] = B_OFF + (wn * 32 + l15) * BK + phys * 8;
  }

  f32x4 acc[4][2];
#pragma unroll
  for (int i = 0; i < 4; ++i)
#pragma unroll
    for (int j = 0; j < 2; ++j)
#pragma unroll
      for (int e = 0; e < 4; ++e) acc[i][j][e] = 0.0f;

  for (int kb = 0; kb < KT; ++kb) {
#pragma unroll
    for (int i = 0; i < 4; ++i) gload_lds16(aSrc[i], lds + aDst[i]);
#pragma unroll
    for (int i = 0; i < 2; ++i) gload_lds16(bSrc[i], lds + bDst[i]);
#pragma unroll
    for (int i = 0; i < 4; ++i) aSrc[i] += BK;
#pragma unroll
    for (int i = 0; i < 2; ++i) bSrc[i] += BK;
    __syncthreads();  // compiler drains vmcnt before barrier

    bf16x8 af[4][2], bfr[2][2];
#pragma unroll
    for (int mi = 0; mi < 4; ++mi)
#pragma unroll
      for (int ks = 0; ks < 2; ++ks)
        af[mi][ks] =
            *reinterpret_cast<const bf16x8*>(lds + aBase[ks] + mi * 1024);
#pragma unroll
    for (int ni = 0; ni < 2; ++ni)
#pragma unroll
      for (int ks = 0; ks < 2; ++ks)
        bfr[ni][ks] =
            *reinterpret_cast<const bf16x8*>(lds + bBase[ks] + ni * 1024);
#pragma unroll
    for (int mi = 0; mi < 4; ++mi)
#pragma unroll
      for (int ni = 0; ni < 2; ++ni) {
        acc[mi][ni] = MFMA16(af[mi][0], bfr[ni][0], acc[mi][ni]);
        acc[mi][ni] = MFMA16(af[mi][1], bfr[ni][1], acc[mi][ni]);
      }
    __syncthreads();
  }

  // ---- epilogue: sparse recurrent + LIF ----
  const float alpha = 0.90483741803595957f;  // exp(-0.1)
  const float beta = 0.81873075307798182f;   // exp(-0.2)
#pragma unroll
  for (int mi = 0; mi < 4; ++mi) {
#pragma unroll
    for (int j = 0; j < 4; ++j) {
      const int r = m0 + wm * 64 + mi * 16 + l4 * 4 + j;
      const int cnt = zcnt[r];
      float rec0 = 0.0f, rec1 = 0.0f;
      const int c0 = n0 + wn * 32 + l15;
      const int c1 = c0 + 16;
      if (cnt > 0) {
        if (cnt <= ZCAP) {  // event-driven path
          const int* zi = zidx + (size_t)r * ZCAP;
          const float* zv = zval + (size_t)r * ZCAP;
          for (int s = 0; s < cnt; ++s) {
            const int o = zi[s];
            const float v = zv[s];
            rec0 += v * recw[(size_t)o * N_DIM + c0];
            rec1 += v * recw[(size_t)o * N_DIM + c1];
          }
        } else {  // dense fallback (general correctness)
          const float* zr = Zin + (size_t)r * N_DIM;
          for (int o = 0; o < N_DIM; ++o) {
            const float v = zr[o];
            if (v != 0.0f) {
              rec0 += v * recw[(size_t)o * N_DIM + c0];
              rec1 += v * recw[(size_t)o * N_DIM + c1];
            }
          }
        }
      }
#pragma unroll
      for (int ni = 0; ni < 2; ++ni) {
        const int c = ni ? c1 : c0;
        const size_t idx = (size_t)r * N_DIM + c;
        const float zin = Zin[idx];
        const float rec = ni ? rec1 : rec0;
        const float nI = alpha * Iin[idx] + acc[mi][ni][j] + rec;
        const float nV = (beta * Vin[idx] + nI) * (1.0f - zin);
        outI[idx] = nI;
        outV[idx] = nV;
        outZ[idx] = (nV > 1.0f) ? 1.0f : 0.0f;
      }
    }
  }
}

extern "C" void kernel_launch(void* const* d_in, const int* in_sizes, int n_in,
                              void* d_out, int out_size, void* d_ws,
                              size_t ws_size, hipStream_t stream) {
  const float* inputs = (const float*)d_in[0];
  const float* I = (const float*)d_in[1];
  const float* V = (const float*)d_in[2];
  const float* Z = (const float*)d_in[3];
  const float* fwd_w = (const float*)d_in[4];
  const float* rec_w = (const float*)d_in[5];

  float* outZ = (float*)d_out;
  float* outI = outZ + (size_t)M_DIM * N_DIM;
  float* outV = outI + (size_t)M_DIM * N_DIM;

  // ws layout: abf 16 MiB | wT 8 MiB | zcnt 16 KiB | zidx 1 MiB | zval 1 MiB
  bf16_t* abf = (bf16_t*)d_ws;
  bf16_t* wT = (bf16_t*)((char*)d_ws + (size_t)M_DIM * K_DIM * 2);
  char* p = (char*)d_ws + (size_t)M_DIM * K_DIM * 2 + (size_t)N_DIM * K_DIM * 2;
  int* zcnt = (int*)p;
  int* zidx = (int*)(p + M_DIM * 4);
  float* zval = (float*)(p + M_DIM * 4 + (size_t)M_DIM * ZCAP * 4);

  hipLaunchKernelGGL(convert_a, dim3((M_DIM * K_DIM) / (256 * 8)), dim3(256),
                     0, stream, inputs, abf);
  hipLaunchKernelGGL(transpose_w, dim3(N_DIM / 64, K_DIM / 64), dim3(256), 0,
                     stream, fwd_w, wT);
  hipLaunchKernelGGL(scan_z, dim3(M_DIM / 4), dim3(256), 0, stream, Z, zcnt,
                     zidx, zval);
  hipLaunchKernelGGL(lif_gemm_tlp, dim3((M_DIM / BM) * (N_DIM / BN)),
                     dim3(256), 0, stream, abf, wT, rec_w, zcnt, zidx, zval, I,
                     V, Z, outZ, outI, outV);
}

// Round 7
// 88.742 us; speedup vs baseline: 1.7581x; 1.1965x over previous
//
#include <hip/hip_runtime.h>
#include <cstdint>
#include <cstddef>

typedef __bf16 bf16_t;
typedef __bf16 bf16x4 __attribute__((ext_vector_type(4)));
typedef __bf16 bf16x8 __attribute__((ext_vector_type(8)));
typedef float f32x4 __attribute__((ext_vector_type(4)));

#define M_DIM 4096
#define K_DIM 2048
#define N_DIM 2048

// ---- fwd GEMM geometry: per-wave 64x64 (32 FLOP/LDS-byte), dbuf ----
#define BM 128
#define BN 128
#define BK 64
#define KT (K_DIM / BK)        // 32 K-tiles
#define A_EL (BM * BK)         // 8192 bf16 (16 KiB)
#define B_EL (BN * BK)         // 8192 bf16 (16 KiB)
#define PER_BUF (A_EL + B_EL)  // 16384 bf16 = 32 KiB
#define B_OFF A_EL

#define ZCAP 64                // spikes kept per row; overflow -> dense path

#define MFMA16(a, b, c) \
  __builtin_amdgcn_mfma_f32_16x16x32_bf16((a), (b), (c), 0, 0, 0)

__device__ __forceinline__ void gload_lds16(const bf16_t* g, bf16_t* l) {
  __builtin_amdgcn_global_load_lds(
      (const __attribute__((address_space(1))) void*)g,
      (__attribute__((address_space(3))) void*)l, 16, 0, 0);
}

// ---------------------------------------------------------------------------
// Prepass 1: inputs f32 [M][K] -> bf16 (k-contiguous), vectorized.
// ---------------------------------------------------------------------------
__global__ __launch_bounds__(256) void convert_a(
    const float* __restrict__ inputs, bf16_t* __restrict__ abf) {
  const int g = blockIdx.x * 256 + threadIdx.x;
  const size_t base = (size_t)g * 8;
  const float4 v0 = *reinterpret_cast<const float4*>(inputs + base);
  const float4 v1 = *reinterpret_cast<const float4*>(inputs + base + 4);
  bf16x8 o;
  o[0] = (bf16_t)v0.x; o[1] = (bf16_t)v0.y;
  o[2] = (bf16_t)v0.z; o[3] = (bf16_t)v0.w;
  o[4] = (bf16_t)v1.x; o[5] = (bf16_t)v1.y;
  o[6] = (bf16_t)v1.z; o[7] = (bf16_t)v1.w;
  *reinterpret_cast<bf16x8*>(abf + base) = o;
}

// ---------------------------------------------------------------------------
// Prepass 2: transpose+convert fwd_w [K][N] f32 -> [N][K] bf16.
// ---------------------------------------------------------------------------
__global__ __launch_bounds__(256) void transpose_w(
    const float* __restrict__ src, bf16_t* __restrict__ dst) {
  __shared__ float tile[64][65];
  const int t = threadIdx.x;
  const int k0 = blockIdx.y * 64;
  const int n0 = blockIdx.x * 64;
#pragma unroll
  for (int p = 0; p < 4; ++p) {
    const int r = p * 16 + (t >> 4);
    const int c = (t & 15) * 4;
    const float4 v = *reinterpret_cast<const float4*>(
        &src[(size_t)(k0 + r) * N_DIM + n0 + c]);
    tile[r][c + 0] = v.x;
    tile[r][c + 1] = v.y;
    tile[r][c + 2] = v.z;
    tile[r][c + 3] = v.w;
  }
  __syncthreads();
#pragma unroll
  for (int p = 0; p < 4; ++p) {
    const int n = p * 16 + (t >> 4);
    const int c = (t & 15) * 4;
    bf16x4 o;
    o[0] = (bf16_t)tile[c + 0][n];
    o[1] = (bf16_t)tile[c + 1][n];
    o[2] = (bf16_t)tile[c + 2][n];
    o[3] = (bf16_t)tile[c + 3][n];
    *reinterpret_cast<bf16x4*>(&dst[(size_t)(n0 + n) * K_DIM + k0 + c]) = o;
  }
}

// ---------------------------------------------------------------------------
// Prepass 3: event-driven compaction of Z (one wave per batch row).
// ---------------------------------------------------------------------------
__global__ __launch_bounds__(256) void scan_z(
    const float* __restrict__ Z, int* __restrict__ zcnt,
    int* __restrict__ zidx, float* __restrict__ zval) {
  const int row = blockIdx.x * 4 + (threadIdx.x >> 6);
  const int lane = threadIdx.x & 63;
  const float* zr = Z + (size_t)row * N_DIM;
  int local = 0;
#pragma unroll
  for (int c = 0; c < 32; c += 4) {
    const f32x4 v = *reinterpret_cast<const f32x4*>(zr + lane * 32 + c);
#pragma unroll
    for (int e = 0; e < 4; ++e) local += (v[e] != 0.0f) ? 1 : 0;
  }
  int pre = local;
#pragma unroll
  for (int d = 1; d < 64; d <<= 1) {
    const int up = __shfl_up(pre, d, 64);
    if (lane >= d) pre += up;
  }
  const int total = __shfl(pre, 63, 64);
  if (lane == 0) zcnt[row] = total;
  if (total > 0 && total <= ZCAP) {
    int wpos = pre - local;
    int* zi = zidx + (size_t)row * ZCAP;
    float* zv = zval + (size_t)row * ZCAP;
    for (int c = lane * 32; c < lane * 32 + 32; ++c) {
      const float v = zr[c];
      if (v != 0.0f) {
        zi[wpos] = c;
        zv[wpos] = v;
        ++wpos;
      }
    }
  }
}

// ---------------------------------------------------------------------------
// Fwd GEMM + sparse recurrent + LIF. BM=BN=128, BK=64, 4 waves (2x2,
// 64x64/wave), double-buffered swizzled LDS, raw barriers, counted vmcnt
// (no vmcnt(0) drain in loop). Vectorized epilogue via LDS transpose;
// Zin never read on the sparse path (gate rebuilt from spike list).
// ---------------------------------------------------------------------------
__global__ __launch_bounds__(256, 2) void lif_gemm_db(
    const bf16_t* __restrict__ A, const bf16_t* __restrict__ W,
    const float* __restrict__ recw,
    const int* __restrict__ zcnt, const int* __restrict__ zidx,
    const float* __restrict__ zval,
    const float* __restrict__ Iin, const float* __restrict__ Vin,
    const float* __restrict__ Zin,
    float* __restrict__ outZ, float* __restrict__ outI,
    float* __restrict__ outV) {
  __shared__ __align__(16) bf16_t lds[2 * PER_BUF];  // 64 KiB

  const int tid = threadIdx.x;
  const int lane = tid & 63;
  const int wave = tid >> 6;   // 0..3
  const int wm = wave >> 1;    // 0..1
  const int wn = wave & 1;     // 0..1
  const int l15 = lane & 15;
  const int l4 = lane >> 4;

  // T1: XCD swizzle (512 blocks, 512%8==0 -> bijective)
  const int bid = blockIdx.x;
  const int swz = (bid & 7) * 64 + (bid >> 3);
  const int m0 = (swz >> 4) * BM;  // 32 m-tiles
  const int n0 = (swz & 15) * BN;  // 16 n-tiles

  // ---- staging (pre-swizzled global source, linear LDS dest; rule 21) ----
  const int lr = lane >> 3;        // 0..7
  const int sg = (lane & 7) ^ lr;  // swizzled 16B-slot
  const bf16_t* aSrc[4];
  const bf16_t* bSrc[4];
  int aDst[4], bDst[4];
#pragma unroll
  for (int i = 0; i < 4; ++i) {
    const int r = wave * 32 + i * 8 + lr;  // rows 0..127
    aSrc[i] = A + (size_t)(m0 + r) * K_DIM + sg * 8;
    aDst[i] = r * BK + (lane & 7) * 8;
    bSrc[i] = W + (size_t)(n0 + r) * K_DIM + sg * 8;
    bDst[i] = B_OFF + r * BK + (lane & 7) * 8;
  }

  // ---- swizzled fragment read bases ----
  int aBase[2], bBase[2];
#pragma unroll
  for (int ks = 0; ks < 2; ++ks) {
    const int phys = (l4 + ks * 4) ^ (l15 & 7);
    aBase[ks] = (wm * 64 + l15) * BK + phys * 8;
    bBase[ks] = B_OFF + (wn * 64 + l15) * BK + phys * 8;
  }

  f32x4 acc[4][4];
#pragma unroll
  for (int i = 0; i < 4; ++i)
#pragma unroll
    for (int j = 0; j < 4; ++j)
#pragma unroll
      for (int e = 0; e < 4; ++e) acc[i][j][e] = 0.0f;

  // ---- prologue: stage tile 0 -> buf0, tile 1 -> buf1 ----
#pragma unroll
  for (int i = 0; i < 4; ++i) {
    gload_lds16(aSrc[i], lds + aDst[i]);
    gload_lds16(bSrc[i], lds + bDst[i]);
  }
#pragma unroll
  for (int i = 0; i < 4; ++i) {
    gload_lds16(aSrc[i] + BK, lds + PER_BUF + aDst[i]);
    gload_lds16(bSrc[i] + BK, lds + PER_BUF + bDst[i]);
  }
  asm volatile("s_waitcnt vmcnt(8)" ::: "memory");  // tile 0 landed (mine)
  __builtin_amdgcn_sched_barrier(0);
  __builtin_amdgcn_s_barrier();                     // everyone's tile 0
  __builtin_amdgcn_sched_barrier(0);

  for (int t = 0; t < KT; ++t) {
    const bf16_t* bufC = lds + (t & 1) * PER_BUF;
    bf16_t* bufS = lds + (t & 1) * PER_BUF;  // t+2 goes where t was

    // ---- ds_read all fragments of tile t ----
    bf16x8 af[4][2], bfr[4][2];
#pragma unroll
    for (int mi = 0; mi < 4; ++mi)
#pragma unroll
      for (int ks = 0; ks < 2; ++ks)
        af[mi][ks] =
            *reinterpret_cast<const bf16x8*>(bufC + aBase[ks] + mi * 1024);
#pragma unroll
    for (int ni = 0; ni < 4; ++ni)
#pragma unroll
      for (int ks = 0; ks < 2; ++ks)
        bfr[ni][ks] =
            *reinterpret_cast<const bf16x8*>(bufC + bBase[ks] + ni * 1024);
    asm volatile("s_waitcnt lgkmcnt(0)" ::: "memory");
    __builtin_amdgcn_sched_barrier(0);
    __builtin_amdgcn_s_barrier();  // all waves done reading buf[t&1]
    __builtin_amdgcn_sched_barrier(0);

    // ---- stage t+2 into buf[t&1] (now safe to overwrite) ----
    if (t + 2 < KT) {
      const int kt = (t + 2) * BK;
#pragma unroll
      for (int i = 0; i < 4; ++i) {
        gload_lds16(aSrc[i] + kt, bufS + aDst[i]);
        gload_lds16(bSrc[i] + kt, bufS + bDst[i]);
      }
    }

    // ---- MFMA tile t (hides t+1/t+2 flight) ----
    __builtin_amdgcn_s_setprio(1);
#pragma unroll
    for (int mi = 0; mi < 4; ++mi)
#pragma unroll
      for (int ni = 0; ni < 4; ++ni) {
        acc[mi][ni] = MFMA16(af[mi][0], bfr[ni][0], acc[mi][ni]);
        acc[mi][ni] = MFMA16(af[mi][1], bfr[ni][1], acc[mi][ni]);
      }
    __builtin_amdgcn_s_setprio(0);
    __builtin_amdgcn_sched_barrier(0);

    // ---- counted wait: tile t+1 landed; t+2's 8 loads stay in flight ----
    if (t + 2 < KT) {
      asm volatile("s_waitcnt vmcnt(8)" ::: "memory");
    } else if (t + 1 < KT) {
      asm volatile("s_waitcnt vmcnt(0)" ::: "memory");
    }
    __builtin_amdgcn_sched_barrier(0);
    __builtin_amdgcn_s_barrier();
    __builtin_amdgcn_sched_barrier(0);
  }

  // ==== epilogue: per-mi LDS transpose -> fully vectorized LIF ====
  const float alpha = 0.90483741803595957f;  // exp(-0.1)
  const float beta = 0.81873075307798182f;   // exp(-0.2)
  float* swp = reinterpret_cast<float*>(lds) + wave * (16 * 66);
  const int er = lane >> 2;            // 0..15 (row within 16-row slab)
  const int ec = (lane & 3) * 4;       // 0,4,8,12

#pragma unroll
  for (int mi = 0; mi < 4; ++mi) {
    // acc -> LDS (stride 66: 2-way max, free)
#pragma unroll
    for (int ni = 0; ni < 4; ++ni)
#pragma unroll
      for (int j = 0; j < 4; ++j)
        swp[(l4 * 4 + j) * 66 + ni * 16 + l15] = acc[mi][ni][j];
    // (compiler inserts lgkmcnt for the same-wave read-after-write)

    const int row = m0 + wm * 64 + mi * 16 + er;
    const int colb = n0 + wn * 64 + ec;  // + cc*16
    const int cnt = zcnt[row];

    f32x4 rec4[4], gate4[4];
#pragma unroll
    for (int cc = 0; cc < 4; ++cc)
#pragma unroll
      for (int e = 0; e < 4; ++e) {
        rec4[cc][e] = 0.0f;
        gate4[cc][e] = 1.0f;
      }
    if (cnt > 0) {
      if (cnt <= ZCAP) {  // event-driven: no Zin read at all
        const int* zi = zidx + (size_t)row * ZCAP;
        const float* zv = zval + (size_t)row * ZCAP;
        for (int s = 0; s < cnt; ++s) {
          const int o = zi[s];
          const float v = zv[s];
          const float* wr = recw + (size_t)o * N_DIM + colb;
#pragma unroll
          for (int cc = 0; cc < 4; ++cc) {
            const f32x4 wv = *reinterpret_cast<const f32x4*>(wr + cc * 16);
#pragma unroll
            for (int e = 0; e < 4; ++e) {
              rec4[cc][e] += v * wv[e];
              gate4[cc][e] = (o == colb + cc * 16 + e) ? (1.0f - v)
                                                       : gate4[cc][e];
            }
          }
        }
      } else {  // dense fallback (general correctness; not taken in bench)
        const float* zr = Zin + (size_t)row * N_DIM;
        for (int o = 0; o < N_DIM; ++o) {
          const float v = zr[o];
          if (v != 0.0f) {
            const float* wr = recw + (size_t)o * N_DIM + colb;
#pragma unroll
            for (int cc = 0; cc < 4; ++cc) {
              const f32x4 wv = *reinterpret_cast<const f32x4*>(wr + cc * 16);
#pragma unroll
              for (int e = 0; e < 4; ++e) {
                rec4[cc][e] += v * wv[e];
                gate4[cc][e] = (o == colb + cc * 16 + e) ? (1.0f - v)
                                                         : gate4[cc][e];
              }
            }
          }
        }
      }
    }

    const size_t gb = (size_t)row * N_DIM + colb;
#pragma unroll
    for (int cc = 0; cc < 4; ++cc) {
      const f32x4 av =
          *reinterpret_cast<const f32x4*>(swp + er * 66 + ec + cc * 16);
      const f32x4 iv = *reinterpret_cast<const f32x4*>(Iin + gb + cc * 16);
      const f32x4 vv = *reinterpret_cast<const f32x4*>(Vin + gb + cc * 16);
      f32x4 nI, nV, nZ;
#pragma unroll
      for (int e = 0; e < 4; ++e) {
        nI[e] = alpha * iv[e] + av[e] + rec4[cc][e];
        nV[e] = (beta * vv[e] + nI[e]) * gate4[cc][e];
        nZ[e] = (nV[e] > 1.0f) ? 1.0f : 0.0f;
      }
      *reinterpret_cast<f32x4*>(outI + gb + cc * 16) = nI;
      *reinterpret_cast<f32x4*>(outV + gb + cc * 16) = nV;
      *reinterpret_cast<f32x4*>(outZ + gb + cc * 16) = nZ;
    }
    // next mi overwrites this wave's private slab; same-wave ordering only
  }
}

extern "C" void kernel_launch(void* const* d_in, const int* in_sizes, int n_in,
                              void* d_out, int out_size, void* d_ws,
                              size_t ws_size, hipStream_t stream) {
  const float* inputs = (const float*)d_in[0];
  const float* I = (const float*)d_in[1];
  const float* V = (const float*)d_in[2];
  const float* Z = (const float*)d_in[3];
  const float* fwd_w = (const float*)d_in[4];
  const float* rec_w = (const float*)d_in[5];

  float* outZ = (float*)d_out;
  float* outI = outZ + (size_t)M_DIM * N_DIM;
  float* outV = outI + (size_t)M_DIM * N_DIM;

  // ws: abf 16 MiB | wT 8 MiB | zcnt 16 KiB | zidx 1 MiB | zval 1 MiB
  bf16_t* abf = (bf16_t*)d_ws;
  bf16_t* wT = (bf16_t*)((char*)d_ws + (size_t)M_DIM * K_DIM * 2);
  char* p = (char*)d_ws + (size_t)M_DIM * K_DIM * 2 + (size_t)N_DIM * K_DIM * 2;
  int* zcnt = (int*)p;
  int* zidx = (int*)(p + M_DIM * 4);
  float* zval = (float*)(p + M_DIM * 4 + (size_t)M_DIM * ZCAP * 4);

  hipLaunchKernelGGL(convert_a, dim3((M_DIM * K_DIM) / (256 * 8)), dim3(256),
                     0, stream, inputs, abf);
  hipLaunchKernelGGL(transpose_w, dim3(N_DIM / 64, K_DIM / 64), dim3(256), 0,
                     stream, fwd_w, wT);
  hipLaunchKernelGGL(scan_z, dim3(M_DIM / 4), dim3(256), 0, stream, Z, zcnt,
                     zidx, zval);
  hipLaunchKernelGGL(lif_gemm_db, dim3((M_DIM / BM) * (N_DIM / BN)),
                     dim3(256), 0, stream, abf, wT, rec_w, zcnt, zidx, zval, I,
                     V, Z, outZ, outI, outV);
}